// Round 8
// baseline (50.999 us; speedup 1.0000x reference)
//
#include <hip/hip_runtime.h>
#include <hip/hip_bf16.h>

typedef __attribute__((ext_vector_type(8))) short short8;
typedef __attribute__((ext_vector_type(4))) float f32x4;
typedef __attribute__((ext_vector_type(4))) unsigned short ushort4n;

#define BLK 256
#define NTILES 6144       // 196608 positions / 32 per tile

// ---- LDS layout (byte offsets) ----
// A1 fragment-native: [kk(9)][rt(2)] chunks of 1024B (64 lanes x 16B), 0..18432.
// After B3 (A1 dead) the same region hosts FMC / A2 / A3 (all disjoint):
#define A1_OFF   0        // 18432 B
#define FMC_OFF  0        // 32 rows x 66 floats = 8448   (written post-B3)
#define A2_OFF   8448     // [kk(2)][rt(2)]x1024 = 4096   (written post-B3)
#define A3_OFF   12544    // [rt(2)]x1024 = 2048          (written post-GEMM2)
#define PART_OFF 18432    // 32 pos x 32 d x float2 (ssum_cat, G_cat) = 8192
#define SMEM_BYTES 26624  // -> 6 blocks/CU (159744 <= 163840)

// ---- workspace layout (bytes) ----
#define WS_B1F  0         // float[64]
#define WS_B2F  256       // float[32]
#define WS_W1F  512       // bf16 [ct(4)][kk(9)][lane(64)][j(8)] = 18432 el = 36864 B
#define WS_W2F  37888     // bf16 [ct(2)][kk(2)][lane][j] = 2048 el = 4096 B
#define WS_W3F  41984     // bf16 [ct(2)][lane][j] = 1024 el = 2048 B
#define WS_WFM  44032     // bf16 [fmct(4)][lane][j] = 2048 el = 4096 B
#define WS_EL   49152     // float2[256000] interleaved (cat_emb, cat_lin)

__global__ void prep_kernel(
    const float* __restrict__ w1, const float* __restrict__ b1,
    const float* __restrict__ g1, const float* __restrict__ bt1,
    const float* __restrict__ m1, const float* __restrict__ v1,
    const float* __restrict__ w2, const float* __restrict__ b2,
    const float* __restrict__ g2, const float* __restrict__ bt2,
    const float* __restrict__ m2, const float* __restrict__ v2,
    const float* __restrict__ w3,
    const float* __restrict__ cat_emb, const float* __restrict__ cat_lin,
    const float* __restrict__ cont_w,  const float* __restrict__ cont_b,
    const float* __restrict__ cont_lw, const float* __restrict__ cont_lb,
    const float* __restrict__ fin_bias,
    float* __restrict__ bias1f, float* __restrict__ bias2f,
    __hip_bfloat16* __restrict__ W1f, __hip_bfloat16* __restrict__ W2f,
    __hip_bfloat16* __restrict__ W3f, __hip_bfloat16* __restrict__ WFMf,
    float2* __restrict__ EL)
{
    int t  = blockIdx.x * blockDim.x + threadIdx.x;
    int nt = gridDim.x * blockDim.x;
    if (t < 64) {
        float s = g1[t] / sqrtf(v1[t] + 1e-5f);
        float cbsum = 0.f;
        for (int f = 0; f < 8; ++f)
            for (int d = 0; d < 32; ++d)
                cbsum += w1[t * 512 + 256 + f * 32 + d] * cont_b[f * 32 + d];
        bias1f[t] = (b1[t] + cbsum - m1[t]) * s + bt1[t];
    }
    if (t >= 64 && t < 96) {
        int o = t - 64;
        float s = g2[o] / sqrtf(v2[o] + 1e-5f);
        bias2f[o] = (b2[o] - m2[o]) * s + bt2[o];
    }
    for (int i = t; i < 8 * 1000 * 32; i += nt) {
        float2 v; v.x = cat_emb[i]; v.y = cat_lin[i];
        EL[i] = v;
    }
    // W1 (h1 only): K=288 rows (256 cat e | 8 c | 24 zero), N=64 cols.
    for (int fi = t; fi < 4 * 9 * 512; fi += nt) {
        int j = fi & 7, lane = (fi >> 3) & 63, t2 = fi >> 9;
        int kk = t2 % 9, ct = t2 / 9;
        int k = kk * 32 + ((lane >> 4) << 3) + j;
        int n = ct * 16 + (lane & 15);
        float s = g1[n] / sqrtf(v1[n] + 1e-5f);
        float val = 0.f;
        if (k < 256) val = s * w1[n * 512 + k];
        else if (k < 264) {
            int f = k - 256; float a = 0.f;
            for (int d = 0; d < 32; ++d)
                a += w1[n * 512 + 256 + f * 32 + d] * cont_w[f * 32 + d];
            val = s * a;
        }
        W1f[fi] = __float2bfloat16(val);
    }
    // WFM: K=32 rows (8 c | 8 c^2 | 1 | 15 zero), N=64 cols (32 ssum_cont | 32 G_cont)
    for (int fi = t; fi < 2048; fi += nt) {
        int j = fi & 7, lane = (fi >> 3) & 63, fmct = fi >> 9;
        int kl = ((lane >> 4) << 3) + j;       // 0..31
        int col = fmct * 16 + (lane & 15);     // 0..63
        int d = col & 31, s = col >> 5;        // s=0: ssum, s=1: G
        float val = 0.f;
        if (s == 0) {
            if (kl < 8) val = cont_w[kl * 32 + d];
            else if (kl == 16) { float a = 0.f; for (int f = 0; f < 8; ++f) a += cont_b[f * 32 + d]; val = a; }
        } else {
            if (kl < 8) val = cont_lw[kl * 32 + d] - cont_w[kl * 32 + d] * cont_b[kl * 32 + d];
            else if (kl < 16) { float w = cont_w[(kl - 8) * 32 + d]; val = -0.5f * w * w; }
            else if (kl == 16) {
                float a = fin_bias[d];
                for (int f = 0; f < 8; ++f)
                    a += cont_lb[f * 32 + d] - 0.5f * cont_b[f * 32 + d] * cont_b[f * 32 + d];
                val = a;
            }
        }
        WFMf[fi] = __float2bfloat16(val);
    }
    // W2 frag order: [ct(2)][kk(2)][lane][j]
    for (int fi = t; fi < 2048; fi += nt) {
        int j = fi & 7, lane = (fi >> 3) & 63, kt = fi >> 9;
        int ct = kt >> 1, kk = kt & 1;
        int k = kk * 32 + ((lane >> 4) << 3) + j;
        int n = ct * 16 + (lane & 15);
        float s = g2[n] / sqrtf(v2[n] + 1e-5f);
        W2f[fi] = __float2bfloat16(s * w2[n * 64 + k]);
    }
    // W3 frag order: [ct(2)][lane][j]
    for (int fi = t; fi < 1024; fi += nt) {
        int j = fi & 7, lane = (fi >> 3) & 63, ct = fi >> 9;
        int k = ((lane >> 4) << 3) + j;
        int n = ct * 16 + (lane & 15);
        W3f[fi] = __float2bfloat16(w3[n * 32 + k]);
    }
}

static __device__ __forceinline__ unsigned short bf16bits(float f) {
    __hip_bfloat16 h = __float2bfloat16(f);
    return *(unsigned short*)&h;
}

__global__ __launch_bounds__(BLK, 6) void fused_kernel(
    const float* __restrict__ x,
    const float* __restrict__ bias1f, const float* __restrict__ bias2f,
    const float* __restrict__ out_b,
    const __hip_bfloat16* __restrict__ W1f,
    const __hip_bfloat16* __restrict__ W2f,
    const __hip_bfloat16* __restrict__ W3f,
    const __hip_bfloat16* __restrict__ WFMf,
    const float2* __restrict__ EL,
    float* __restrict__ out)
{
    __shared__ __align__(16) char smem[SMEM_BYTES];
    const int tid  = threadIdx.x;
    const int lane = tid & 63;
    const int wv   = tid >> 6;
    const int tile = blockIdx.x;
    const int rt2 = wv >> 1, ct2 = wv & 1;

    // ---- Phase A: cat gathers; fp32 ssum_cat/G_cat; A1 fragments.
    //      x read directly (8 threads/row -> L1 broadcast). ----
    {
        const int p = tid >> 3, d0 = (tid & 7) << 2, g = d0 >> 3, rtp = p >> 4;
        const float* xp = x + (size_t)tile * 512 + p * 16;
        float4 xi0 = ((const float4*)xp)[0];
        float4 xi1 = ((const float4*)xp)[1];
        float4 xc0 = ((const float4*)xp)[2];
        float4 xc1 = ((const float4*)xp)[3];
        float idxf[8] = {xi0.x, xi0.y, xi0.z, xi0.w, xi1.x, xi1.y, xi1.z, xi1.w};
        float cf[8]   = {xc0.x, xc0.y, xc0.z, xc0.w, xc1.x, xc1.y, xc1.z, xc1.w};

        float4 ssum = {0.f, 0.f, 0.f, 0.f};
        float4 lin  = {0.f, 0.f, 0.f, 0.f};
        float4 ssq  = {0.f, 0.f, 0.f, 0.f};

        char* aw = smem + A1_OFF + rtp * 1024 + ((p & 15) + 16 * g) * 16 + (d0 & 7) * 2;
        #pragma unroll
        for (int f = 0; f < 8; ++f) {
            int ix = (int)idxf[f];
            const float4* src = (const float4*)(EL + ((f * 1000 + ix) * 32 + d0));
            float4 v0 = src[0], v1 = src[1];
            float4 e  = {v0.x, v0.z, v1.x, v1.z};
            float4 el = {v0.y, v0.w, v1.y, v1.w};
            ssum += e; ssq += e * e; lin += el;
            ushort4n ev = {bf16bits(e.x), bf16bits(e.y), bf16bits(e.z), bf16bits(e.w)};
            *(ushort4n*)(aw + f * 2048) = ev;
        }
        // kk=8 chunk: rows [c(8) | c^2(8) | 1 | 0...] selected by d0-group g
        {
            char* c8 = smem + A1_OFF + 8 * 2048 + rtp * 1024 + ((p & 15) + 16 * g) * 16;
            ushort4n lo = {0, 0, 0, 0}, hi = {0, 0, 0, 0};
            if (g == 0) {
                lo = (ushort4n){bf16bits(cf[0]), bf16bits(cf[1]), bf16bits(cf[2]), bf16bits(cf[3])};
                hi = (ushort4n){bf16bits(cf[4]), bf16bits(cf[5]), bf16bits(cf[6]), bf16bits(cf[7])};
            } else if (g == 1) {
                lo = (ushort4n){bf16bits(cf[0]*cf[0]), bf16bits(cf[1]*cf[1]), bf16bits(cf[2]*cf[2]), bf16bits(cf[3]*cf[3])};
                hi = (ushort4n){bf16bits(cf[4]*cf[4]), bf16bits(cf[5]*cf[5]), bf16bits(cf[6]*cf[6]), bf16bits(cf[7]*cf[7])};
            } else if (g == 2) {
                lo = (ushort4n){0x3F80, 0, 0, 0};          // 1.0 then zeros
            }
            *(ushort4n*)c8 = lo;
            *(ushort4n*)(c8 + 8) = hi;
        }
        // PART: (ssum_cat, G_cat) float2 per (p,d)
        float4 G;
        G.x = lin.x - 0.5f * ssq.x; G.y = lin.y - 0.5f * ssq.y;
        G.z = lin.z - 0.5f * ssq.z; G.w = lin.w - 0.5f * ssq.w;
        float4 o0 = {ssum.x, G.x, ssum.y, G.y};
        float4 o1 = {ssum.z, G.z, ssum.w, G.w};
        *(float4*)(smem + PART_OFF + (p * 32 + d0) * 8)      = o0;
        *(float4*)(smem + PART_OFF + (p * 32 + d0) * 8 + 16) = o1;
    }
    __syncthreads();                                        // B2: A1/PART ready

    // ---- GEMM1 (h1, N=64) + FM mini-GEMM over the kk=8 chunk ----
    const short8* W1v  = (const short8*)W1f;
    const short8* WFMv = (const short8*)WFMf;
    f32x4 ah0 = {0,0,0,0}, ah1 = {0,0,0,0};
    f32x4 fm0 = {0,0,0,0}, fm1 = {0,0,0,0};
    #pragma unroll
    for (int kk = 0; kk < 9; ++kk) {
        short8 b  = W1v[(wv * 9 + kk) * 64 + lane];
        short8 a0 = *(const short8*)(smem + A1_OFF + kk * 2048 + lane * 16);
        short8 a1 = *(const short8*)(smem + A1_OFF + kk * 2048 + 1024 + lane * 16);
        ah0 = __builtin_amdgcn_mfma_f32_16x16x32_bf16(a0, b, ah0, 0, 0, 0);
        ah1 = __builtin_amdgcn_mfma_f32_16x16x32_bf16(a1, b, ah1, 0, 0, 0);
        if (kk == 8) {
            short8 bfm = WFMv[wv * 64 + lane];
            fm0 = __builtin_amdgcn_mfma_f32_16x16x32_bf16(a0, bfm, fm0, 0, 0, 0);
            fm1 = __builtin_amdgcn_mfma_f32_16x16x32_bf16(a1, bfm, fm1, 0, 0, 0);
        }
    }
    __syncthreads();                                        // B3: A1 dead

    // ---- h1 -> A2 fragments; FM results -> FMC (both in dead A1 region) ----
    {
        const float bo1 = bias1f[wv * 16 + (lane & 15)];
        const int coll = (wv * 16 + (lane & 15)) & 31;
        const int kk2 = wv >> 1;
        const int nsub = coll >> 3;
        const int jof = (coll & 7) * 2;
        const int rbase = (lane >> 4) << 2;
        #pragma unroll
        for (int rt = 0; rt < 2; ++rt) {
            f32x4 acc = rt ? ah1 : ah0;
            #pragma unroll
            for (int r = 0; r < 4; ++r) {
                float h = fmaxf(acc[r] + bo1, 0.f);
                *(__hip_bfloat16*)(smem + A2_OFF + (kk2 * 2 + rt) * 1024 + ((rbase + r) + 16 * nsub) * 16 + jof)
                    = __float2bfloat16(h);
            }
        }
        const int colf = wv * 16 + (lane & 15);             // 0..63
        const int d = colf & 31, s = colf >> 5;
        #pragma unroll
        for (int rt = 0; rt < 2; ++rt) {
            f32x4 acc = rt ? fm1 : fm0;
            #pragma unroll
            for (int r = 0; r < 4; ++r) {
                int row = rt * 16 + rbase + r;
                *(float*)(smem + FMC_OFF + (row * 66 + d * 2 + s) * 4) = acc[r];
            }
        }
    }
    __syncthreads();                                        // B4

    // ---- GEMM2: (32 x 64) x (64 x 32) ----
    const short8* W2v = (const short8*)W2f;
    f32x4 acc2 = {0,0,0,0};
    {
        short8 b0 = W2v[(ct2 * 2 + 0) * 64 + lane];
        short8 b1 = W2v[(ct2 * 2 + 1) * 64 + lane];
        short8 a0 = *(const short8*)(smem + A2_OFF + (0 * 2 + rt2) * 1024 + lane * 16);
        acc2 = __builtin_amdgcn_mfma_f32_16x16x32_bf16(a0, b0, acc2, 0, 0, 0);
        short8 a1 = *(const short8*)(smem + A2_OFF + (1 * 2 + rt2) * 1024 + lane * 16);
        acc2 = __builtin_amdgcn_mfma_f32_16x16x32_bf16(a1, b1, acc2, 0, 0, 0);
    }
    // h2 -> A3 fragments
    {
        const float bo2 = bias2f[ct2 * 16 + (lane & 15)];
        const int col2 = ct2 * 16 + (lane & 15);
        const int nsub2 = col2 >> 3;
        const int jof = (col2 & 7) * 2;
        const int rbase = (lane >> 4) << 2;
        #pragma unroll
        for (int r = 0; r < 4; ++r) {
            float h = fmaxf(acc2[r] + bo2, 0.f);
            *(__hip_bfloat16*)(smem + A3_OFF + rt2 * 1024 + ((rbase + r) + 16 * nsub2) * 16 + jof)
                = __float2bfloat16(h);
        }
    }
    __syncthreads();                                        // B5

    // ---- GEMM3 + epilogue ----
    {
        const short8* W3v = (const short8*)W3f;
        short8 b3 = W3v[ct2 * 64 + lane];
        short8 a3 = *(const short8*)(smem + A3_OFF + rt2 * 1024 + lane * 16);
        f32x4 z = {0,0,0,0};
        f32x4 acc3 = __builtin_amdgcn_mfma_f32_16x16x32_bf16(a3, b3, z, 0, 0, 0);

        const int dcol = ct2 * 16 + (lane & 15);
        const float ob = out_b[dcol];
        const int rbase = (lane >> 4) << 2;
        size_t outbase = (size_t)tile * 1024;
        #pragma unroll
        for (int r = 0; r < 4; ++r) {
            int p = rt2 * 16 + rbase + r;
            float2 sg = *(const float2*)(smem + FMC_OFF + (p * 66 + dcol * 2) * 4);   // (ssum_cont, G_cont)
            float2 pc = *(const float2*)(smem + PART_OFF + (p * 32 + dcol) * 8);      // (ssum_cat, G_cat)
            float S = pc.x + sg.x;
            out[outbase + p * 32 + dcol] = acc3[r] + ob + pc.y + sg.y + 0.5f * S * S;
        }
    }
}

extern "C" void kernel_launch(void* const* d_in, const int* in_sizes, int n_in,
                              void* d_out, int out_size, void* d_ws, size_t ws_size,
                              hipStream_t stream) {
    const float* x        = (const float*)d_in[0];
    const float* cat_emb  = (const float*)d_in[1];
    const float* cat_lin  = (const float*)d_in[2];
    const float* cont_w   = (const float*)d_in[3];
    const float* cont_b   = (const float*)d_in[4];
    const float* cont_lw  = (const float*)d_in[5];
    const float* cont_lb  = (const float*)d_in[6];
    const float* fin_bias = (const float*)d_in[7];
    const float* dnn1_w   = (const float*)d_in[8];
    const float* dnn1_b   = (const float*)d_in[9];
    const float* bn1_g    = (const float*)d_in[10];
    const float* bn1_bt   = (const float*)d_in[11];
    const float* bn1_m    = (const float*)d_in[12];
    const float* bn1_v    = (const float*)d_in[13];
    const float* dnn2_w   = (const float*)d_in[14];
    const float* dnn2_b   = (const float*)d_in[15];
    const float* bn2_g    = (const float*)d_in[16];
    const float* bn2_bt   = (const float*)d_in[17];
    const float* bn2_m    = (const float*)d_in[18];
    const float* bn2_v    = (const float*)d_in[19];
    const float* out_w    = (const float*)d_in[20];
    const float* out_b    = (const float*)d_in[21];

    char* ws = (char*)d_ws;
    float* bias1f = (float*)(ws + WS_B1F);
    float* bias2f = (float*)(ws + WS_B2F);
    __hip_bfloat16* W1f  = (__hip_bfloat16*)(ws + WS_W1F);
    __hip_bfloat16* W2f  = (__hip_bfloat16*)(ws + WS_W2F);
    __hip_bfloat16* W3f  = (__hip_bfloat16*)(ws + WS_W3F);
    __hip_bfloat16* WFMf = (__hip_bfloat16*)(ws + WS_WFM);
    float2* EL = (float2*)(ws + WS_EL);

    hipLaunchKernelGGL(prep_kernel, dim3(256), dim3(BLK), 0, stream,
                       dnn1_w, dnn1_b, bn1_g, bn1_bt, bn1_m, bn1_v,
                       dnn2_w, dnn2_b, bn2_g, bn2_bt, bn2_m, bn2_v,
                       out_w, cat_emb, cat_lin, cont_w, cont_b, cont_lw, cont_lb,
                       fin_bias, bias1f, bias2f, W1f, W2f, W3f, WFMf, EL);

    hipLaunchKernelGGL(fused_kernel, dim3(NTILES), dim3(BLK), 0, stream,
                       x, bias1f, bias2f, out_b, W1f, W2f, W3f, WFMf, EL,
                       (float*)d_out);
}

// Round 9
// 40.970 us; speedup vs baseline: 1.2448x; 1.2448x over previous
//
#include <hip/hip_runtime.h>
#include <hip/hip_bf16.h>

typedef __attribute__((ext_vector_type(8))) short short8;
typedef __attribute__((ext_vector_type(4))) float f32x4;
typedef __attribute__((ext_vector_type(4))) unsigned short ushort4n;

#define BLK 256
#define NTILES 6144       // 196608 positions / 32 per tile

// ---- LDS layout (byte offsets) ----
// A1 fragment-native: [kk(9)][rt(2)] chunks of 1024B (64 lanes x 16B), 0..18432.
// After B3 (A1 dead) the same region hosts FMC / A2 / A3 (all disjoint):
#define A1_OFF   0        // 18432 B
#define FMC_OFF  0        // 32 rows x 66 floats = 8448   (written post-B3)
#define A2_OFF   8448     // [kk(2)][rt(2)]x1024 = 4096   (written post-B3)
#define A3_OFF   12544    // [rt(2)]x1024 = 2048          (written post-GEMM2)
#define PART_OFF 18432    // 32 pos x 32 d x float2 (ssum_cat, G_cat) = 8192
#define XS_OFF   26624    // x stage 32x64B = 2048
#define SMEM_BYTES 28672  // -> 5 blocks/CU

// ---- workspace layout (bytes) ----
#define WS_B1F  0         // float[64]
#define WS_B2F  256       // float[32]
#define WS_W1F  512       // bf16 [ct(4)][kk(9)][lane(64)][j(8)] = 18432 el = 36864 B
#define WS_W2F  37888     // bf16 [ct(2)][kk(2)][lane][j] = 2048 el = 4096 B
#define WS_W3F  41984     // bf16 [ct(2)][lane][j] = 1024 el = 2048 B
#define WS_WFM  44032     // bf16 [fmct(4)][lane][j] = 2048 el = 4096 B
#define WS_EL   49152     // uint[256000]: (bf16 e) | (bf16 el)<<16 = 1.024 MB

__global__ void prep_kernel(
    const float* __restrict__ w1, const float* __restrict__ b1,
    const float* __restrict__ g1, const float* __restrict__ bt1,
    const float* __restrict__ m1, const float* __restrict__ v1,
    const float* __restrict__ w2, const float* __restrict__ b2,
    const float* __restrict__ g2, const float* __restrict__ bt2,
    const float* __restrict__ m2, const float* __restrict__ v2,
    const float* __restrict__ w3,
    const float* __restrict__ cat_emb, const float* __restrict__ cat_lin,
    const float* __restrict__ cont_w,  const float* __restrict__ cont_b,
    const float* __restrict__ cont_lw, const float* __restrict__ cont_lb,
    const float* __restrict__ fin_bias,
    float* __restrict__ bias1f, float* __restrict__ bias2f,
    __hip_bfloat16* __restrict__ W1f, __hip_bfloat16* __restrict__ W2f,
    __hip_bfloat16* __restrict__ W3f, __hip_bfloat16* __restrict__ WFMf,
    unsigned* __restrict__ ELb)
{
    int t  = blockIdx.x * blockDim.x + threadIdx.x;
    int nt = gridDim.x * blockDim.x;
    if (t < 64) {
        float s = g1[t] / sqrtf(v1[t] + 1e-5f);
        float cbsum = 0.f;
        for (int f = 0; f < 8; ++f)
            for (int d = 0; d < 32; ++d)
                cbsum += w1[t * 512 + 256 + f * 32 + d] * cont_b[f * 32 + d];
        bias1f[t] = (b1[t] + cbsum - m1[t]) * s + bt1[t];
    }
    if (t >= 64 && t < 96) {
        int o = t - 64;
        float s = g2[o] / sqrtf(v2[o] + 1e-5f);
        bias2f[o] = (b2[o] - m2[o]) * s + bt2[o];
    }
    for (int i = t; i < 8 * 1000 * 32; i += nt) {
        __hip_bfloat16 eb = __float2bfloat16(cat_emb[i]);
        __hip_bfloat16 lb = __float2bfloat16(cat_lin[i]);
        unsigned eu = *(unsigned short*)&eb;
        unsigned lu = *(unsigned short*)&lb;
        ELb[i] = eu | (lu << 16);
    }
    // W1 (h1 only): K=288 rows (256 cat e | 8 c | 24 zero), N=64 cols.
    for (int fi = t; fi < 4 * 9 * 512; fi += nt) {
        int j = fi & 7, lane = (fi >> 3) & 63, t2 = fi >> 9;
        int kk = t2 % 9, ct = t2 / 9;
        int k = kk * 32 + ((lane >> 4) << 3) + j;
        int n = ct * 16 + (lane & 15);
        float s = g1[n] / sqrtf(v1[n] + 1e-5f);
        float val = 0.f;
        if (k < 256) val = s * w1[n * 512 + k];
        else if (k < 264) {
            int f = k - 256; float a = 0.f;
            for (int d = 0; d < 32; ++d)
                a += w1[n * 512 + 256 + f * 32 + d] * cont_w[f * 32 + d];
            val = s * a;
        }
        W1f[fi] = __float2bfloat16(val);
    }
    // WFM: K=32 rows (8 c | 8 c^2 | 1 | 15 zero), N=64 cols (32 ssum_cont | 32 G_cont)
    for (int fi = t; fi < 2048; fi += nt) {
        int j = fi & 7, lane = (fi >> 3) & 63, fmct = fi >> 9;
        int kl = ((lane >> 4) << 3) + j;       // 0..31
        int col = fmct * 16 + (lane & 15);     // 0..63
        int d = col & 31, s = col >> 5;        // s=0: ssum, s=1: G
        float val = 0.f;
        if (s == 0) {
            if (kl < 8) val = cont_w[kl * 32 + d];
            else if (kl == 16) { float a = 0.f; for (int f = 0; f < 8; ++f) a += cont_b[f * 32 + d]; val = a; }
        } else {
            if (kl < 8) val = cont_lw[kl * 32 + d] - cont_w[kl * 32 + d] * cont_b[kl * 32 + d];
            else if (kl < 16) { float w = cont_w[(kl - 8) * 32 + d]; val = -0.5f * w * w; }
            else if (kl == 16) {
                float a = fin_bias[d];
                for (int f = 0; f < 8; ++f)
                    a += cont_lb[f * 32 + d] - 0.5f * cont_b[f * 32 + d] * cont_b[f * 32 + d];
                val = a;
            }
        }
        WFMf[fi] = __float2bfloat16(val);
    }
    // W2 frag order: [ct(2)][kk(2)][lane][j]
    for (int fi = t; fi < 2048; fi += nt) {
        int j = fi & 7, lane = (fi >> 3) & 63, kt = fi >> 9;
        int ct = kt >> 1, kk = kt & 1;
        int k = kk * 32 + ((lane >> 4) << 3) + j;
        int n = ct * 16 + (lane & 15);
        float s = g2[n] / sqrtf(v2[n] + 1e-5f);
        W2f[fi] = __float2bfloat16(s * w2[n * 64 + k]);
    }
    // W3 frag order: [ct(2)][lane][j]
    for (int fi = t; fi < 1024; fi += nt) {
        int j = fi & 7, lane = (fi >> 3) & 63, ct = fi >> 9;
        int k = ((lane >> 4) << 3) + j;
        int n = ct * 16 + (lane & 15);
        W3f[fi] = __float2bfloat16(w3[n * 32 + k]);
    }
}

static __device__ __forceinline__ unsigned short bf16bits(float f) {
    __hip_bfloat16 h = __float2bfloat16(f);
    return *(unsigned short*)&h;
}

__global__ __launch_bounds__(BLK, 5) void fused_kernel(
    const float* __restrict__ x,
    const float* __restrict__ bias1f, const float* __restrict__ bias2f,
    const float* __restrict__ out_b,
    const __hip_bfloat16* __restrict__ W1f,
    const __hip_bfloat16* __restrict__ W2f,
    const __hip_bfloat16* __restrict__ W3f,
    const __hip_bfloat16* __restrict__ WFMf,
    const unsigned* __restrict__ ELb,
    float* __restrict__ out)
{
    __shared__ __align__(16) char smem[SMEM_BYTES];
    const int tid  = threadIdx.x;
    const int lane = tid & 63;
    const int wv   = tid >> 6;
    const int tile = blockIdx.x;
    const int rt2 = wv >> 1, ct2 = wv & 1;

    // ---- stage x (32 pos x 16 feat): one coalesced read ----
    if (tid < 128)
        ((float4*)(smem + XS_OFF))[tid] = ((const float4*)(x + (size_t)tile * 512))[tid];
    __syncthreads();                                        // B1

    // ---- Phase A: packed-bf16 cat gathers; fp32 ssum_cat/G_cat; A1 frags ----
    {
        const int p = tid >> 3, d0 = (tid & 7) << 2, g = d0 >> 3, rtp = p >> 4;
        const float* xs = (const float*)(smem + XS_OFF) + p * 16;
        float4 xi0 = ((const float4*)xs)[0];
        float4 xi1 = ((const float4*)xs)[1];
        float4 xc0 = ((const float4*)xs)[2];
        float4 xc1 = ((const float4*)xs)[3];
        float idxf[8] = {xi0.x, xi0.y, xi0.z, xi0.w, xi1.x, xi1.y, xi1.z, xi1.w};
        float cf[8]   = {xc0.x, xc0.y, xc0.z, xc0.w, xc1.x, xc1.y, xc1.z, xc1.w};

        float4 ssum = {0.f, 0.f, 0.f, 0.f};
        float4 lin  = {0.f, 0.f, 0.f, 0.f};
        float4 ssq  = {0.f, 0.f, 0.f, 0.f};

        char* aw = smem + A1_OFF + rtp * 1024 + ((p & 15) + 16 * g) * 16 + (d0 & 7) * 2;
        #pragma unroll
        for (int f = 0; f < 8; ++f) {
            int ix = (int)idxf[f];
            uint4 v = *(const uint4*)(ELb + ((f * 1000 + ix) * 32 + d0));
            float e0 = __uint_as_float(v.x << 16), l0 = __uint_as_float(v.x & 0xFFFF0000u);
            float e1 = __uint_as_float(v.y << 16), l1 = __uint_as_float(v.y & 0xFFFF0000u);
            float e2 = __uint_as_float(v.z << 16), l2 = __uint_as_float(v.z & 0xFFFF0000u);
            float e3 = __uint_as_float(v.w << 16), l3 = __uint_as_float(v.w & 0xFFFF0000u);
            ssum.x += e0; ssum.y += e1; ssum.z += e2; ssum.w += e3;
            ssq.x = fmaf(e0, e0, ssq.x); ssq.y = fmaf(e1, e1, ssq.y);
            ssq.z = fmaf(e2, e2, ssq.z); ssq.w = fmaf(e3, e3, ssq.w);
            lin.x += l0; lin.y += l1; lin.z += l2; lin.w += l3;
            ushort4n ev = {(unsigned short)v.x, (unsigned short)v.y,
                           (unsigned short)v.z, (unsigned short)v.w};
            *(ushort4n*)(aw + f * 2048) = ev;
        }
        // kk=8 chunk: rows [c(8) | c^2(8) | 1 | 0...] selected by d0-group g
        {
            char* c8 = smem + A1_OFF + 8 * 2048 + rtp * 1024 + ((p & 15) + 16 * g) * 16;
            ushort4n lo = {0, 0, 0, 0}, hi = {0, 0, 0, 0};
            if (g == 0) {
                lo = (ushort4n){bf16bits(cf[0]), bf16bits(cf[1]), bf16bits(cf[2]), bf16bits(cf[3])};
                hi = (ushort4n){bf16bits(cf[4]), bf16bits(cf[5]), bf16bits(cf[6]), bf16bits(cf[7])};
            } else if (g == 1) {
                lo = (ushort4n){bf16bits(cf[0]*cf[0]), bf16bits(cf[1]*cf[1]), bf16bits(cf[2]*cf[2]), bf16bits(cf[3]*cf[3])};
                hi = (ushort4n){bf16bits(cf[4]*cf[4]), bf16bits(cf[5]*cf[5]), bf16bits(cf[6]*cf[6]), bf16bits(cf[7]*cf[7])};
            } else if (g == 2) {
                lo = (ushort4n){0x3F80, 0, 0, 0};          // 1.0 then zeros
            }
            *(ushort4n*)c8 = lo;
            *(ushort4n*)(c8 + 8) = hi;
        }
        // PART: (ssum_cat, G_cat) float2 per (p,d)
        float4 G;
        G.x = lin.x - 0.5f * ssq.x; G.y = lin.y - 0.5f * ssq.y;
        G.z = lin.z - 0.5f * ssq.z; G.w = lin.w - 0.5f * ssq.w;
        float4 o0 = {ssum.x, G.x, ssum.y, G.y};
        float4 o1 = {ssum.z, G.z, ssum.w, G.w};
        *(float4*)(smem + PART_OFF + (p * 32 + d0) * 8)      = o0;
        *(float4*)(smem + PART_OFF + (p * 32 + d0) * 8 + 16) = o1;
    }
    __syncthreads();                                        // B2: A1/PART ready

    // ---- GEMM1 (h1, N=64) + FM mini-GEMM over the kk=8 chunk ----
    const short8* W1v  = (const short8*)W1f;
    const short8* WFMv = (const short8*)WFMf;
    f32x4 ah0 = {0,0,0,0}, ah1 = {0,0,0,0};
    f32x4 fm0 = {0,0,0,0}, fm1 = {0,0,0,0};
    #pragma unroll
    for (int kk = 0; kk < 9; ++kk) {
        short8 b  = W1v[(wv * 9 + kk) * 64 + lane];
        short8 a0 = *(const short8*)(smem + A1_OFF + kk * 2048 + lane * 16);
        short8 a1 = *(const short8*)(smem + A1_OFF + kk * 2048 + 1024 + lane * 16);
        ah0 = __builtin_amdgcn_mfma_f32_16x16x32_bf16(a0, b, ah0, 0, 0, 0);
        ah1 = __builtin_amdgcn_mfma_f32_16x16x32_bf16(a1, b, ah1, 0, 0, 0);
        if (kk == 8) {
            short8 bfm = WFMv[wv * 64 + lane];
            fm0 = __builtin_amdgcn_mfma_f32_16x16x32_bf16(a0, bfm, fm0, 0, 0, 0);
            fm1 = __builtin_amdgcn_mfma_f32_16x16x32_bf16(a1, bfm, fm1, 0, 0, 0);
        }
    }
    __syncthreads();                                        // B3: A1 dead

    // ---- h1 -> A2 fragments; FM results -> FMC (both in dead A1 region) ----
    {
        const float bo1 = bias1f[wv * 16 + (lane & 15)];
        const int coll = (wv * 16 + (lane & 15)) & 31;
        const int kk2 = wv >> 1;
        const int nsub = coll >> 3;
        const int jof = (coll & 7) * 2;
        const int rbase = (lane >> 4) << 2;
        #pragma unroll
        for (int rt = 0; rt < 2; ++rt) {
            f32x4 acc = rt ? ah1 : ah0;
            #pragma unroll
            for (int r = 0; r < 4; ++r) {
                float h = fmaxf(acc[r] + bo1, 0.f);
                *(__hip_bfloat16*)(smem + A2_OFF + (kk2 * 2 + rt) * 1024 + ((rbase + r) + 16 * nsub) * 16 + jof)
                    = __float2bfloat16(h);
            }
        }
        const int colf = wv * 16 + (lane & 15);             // 0..63
        const int d = colf & 31, s = colf >> 5;
        #pragma unroll
        for (int rt = 0; rt < 2; ++rt) {
            f32x4 acc = rt ? fm1 : fm0;
            #pragma unroll
            for (int r = 0; r < 4; ++r) {
                int row = rt * 16 + rbase + r;
                *(float*)(smem + FMC_OFF + (row * 66 + d * 2 + s) * 4) = acc[r];
            }
        }
    }
    __syncthreads();                                        // B4

    // ---- GEMM2: (32 x 64) x (64 x 32) ----
    const short8* W2v = (const short8*)W2f;
    f32x4 acc2 = {0,0,0,0};
    {
        short8 b0 = W2v[(ct2 * 2 + 0) * 64 + lane];
        short8 b1 = W2v[(ct2 * 2 + 1) * 64 + lane];
        short8 a0 = *(const short8*)(smem + A2_OFF + (0 * 2 + rt2) * 1024 + lane * 16);
        acc2 = __builtin_amdgcn_mfma_f32_16x16x32_bf16(a0, b0, acc2, 0, 0, 0);
        short8 a1 = *(const short8*)(smem + A2_OFF + (1 * 2 + rt2) * 1024 + lane * 16);
        acc2 = __builtin_amdgcn_mfma_f32_16x16x32_bf16(a1, b1, acc2, 0, 0, 0);
    }
    // h2 -> A3 fragments
    {
        const float bo2 = bias2f[ct2 * 16 + (lane & 15)];
        const int col2 = ct2 * 16 + (lane & 15);
        const int nsub2 = col2 >> 3;
        const int jof = (col2 & 7) * 2;
        const int rbase = (lane >> 4) << 2;
        #pragma unroll
        for (int r = 0; r < 4; ++r) {
            float h = fmaxf(acc2[r] + bo2, 0.f);
            *(__hip_bfloat16*)(smem + A3_OFF + rt2 * 1024 + ((rbase + r) + 16 * nsub2) * 16 + jof)
                = __float2bfloat16(h);
        }
    }
    __syncthreads();                                        // B5

    // ---- GEMM3 + epilogue ----
    {
        const short8* W3v = (const short8*)W3f;
        short8 b3 = W3v[ct2 * 64 + lane];
        short8 a3 = *(const short8*)(smem + A3_OFF + rt2 * 1024 + lane * 16);
        f32x4 z = {0,0,0,0};
        f32x4 acc3 = __builtin_amdgcn_mfma_f32_16x16x32_bf16(a3, b3, z, 0, 0, 0);

        const int dcol = ct2 * 16 + (lane & 15);
        const float ob = out_b[dcol];
        const int rbase = (lane >> 4) << 2;
        size_t outbase = (size_t)tile * 1024;
        #pragma unroll
        for (int r = 0; r < 4; ++r) {
            int p = rt2 * 16 + rbase + r;
            float2 sg = *(const float2*)(smem + FMC_OFF + (p * 66 + dcol * 2) * 4);   // (ssum_cont, G_cont)
            float2 pc = *(const float2*)(smem + PART_OFF + (p * 32 + dcol) * 8);      // (ssum_cat, G_cat)
            float S = pc.x + sg.x;
            out[outbase + p * 32 + dcol] = acc3[r] + ob + pc.y + sg.y + 0.5f * S * S;
        }
    }
}

extern "C" void kernel_launch(void* const* d_in, const int* in_sizes, int n_in,
                              void* d_out, int out_size, void* d_ws, size_t ws_size,
                              hipStream_t stream) {
    const float* x        = (const float*)d_in[0];
    const float* cat_emb  = (const float*)d_in[1];
    const float* cat_lin  = (const float*)d_in[2];
    const float* cont_w   = (const float*)d_in[3];
    const float* cont_b   = (const float*)d_in[4];
    const float* cont_lw  = (const float*)d_in[5];
    const float* cont_lb  = (const float*)d_in[6];
    const float* fin_bias = (const float*)d_in[7];
    const float* dnn1_w   = (const float*)d_in[8];
    const float* dnn1_b   = (const float*)d_in[9];
    const float* bn1_g    = (const float*)d_in[10];
    const float* bn1_bt   = (const float*)d_in[11];
    const float* bn1_m    = (const float*)d_in[12];
    const float* bn1_v    = (const float*)d_in[13];
    const float* dnn2_w   = (const float*)d_in[14];
    const float* dnn2_b   = (const float*)d_in[15];
    const float* bn2_g    = (const float*)d_in[16];
    const float* bn2_bt   = (const float*)d_in[17];
    const float* bn2_m    = (const float*)d_in[18];
    const float* bn2_v    = (const float*)d_in[19];
    const float* out_w    = (const float*)d_in[20];
    const float* out_b    = (const float*)d_in[21];

    char* ws = (char*)d_ws;
    float* bias1f = (float*)(ws + WS_B1F);
    float* bias2f = (float*)(ws + WS_B2F);
    __hip_bfloat16* W1f  = (__hip_bfloat16*)(ws + WS_W1F);
    __hip_bfloat16* W2f  = (__hip_bfloat16*)(ws + WS_W2F);
    __hip_bfloat16* W3f  = (__hip_bfloat16*)(ws + WS_W3F);
    __hip_bfloat16* WFMf = (__hip_bfloat16*)(ws + WS_WFM);
    unsigned* ELb = (unsigned*)(ws + WS_EL);

    hipLaunchKernelGGL(prep_kernel, dim3(256), dim3(BLK), 0, stream,
                       dnn1_w, dnn1_b, bn1_g, bn1_bt, bn1_m, bn1_v,
                       dnn2_w, dnn2_b, bn2_g, bn2_bt, bn2_m, bn2_v,
                       out_w, cat_emb, cat_lin, cont_w, cont_b, cont_lw, cont_lb,
                       fin_bias, bias1f, bias2f, W1f, W2f, W3f, WFMf, ELb);

    hipLaunchKernelGGL(fused_kernel, dim3(NTILES), dim3(BLK), 0, stream,
                       x, bias1f, bias2f, out_b, W1f, W2f, W3f, WFMf, ELb,
                       (float*)d_out);
}